// Round 11
// baseline (78.196 us; speedup 1.0000x reference)
//
#include <hip/hip_runtime.h>
#include <cstdint>

#define IN_FEAT 256
#define OUT_FEAT 64

constexpr int RPW = 16;             // rows per wave in scatter

typedef __attribute__((ext_vector_type(4))) float f32x4;
typedef __attribute__((ext_vector_type(8))) _Float16 f16x8;

union HF8 { _Float16 h[8]; f16x8 v; };

// ---------------------------------------------------------------------------
// Kernel 1: proj(fp16) = feat @ W via mfma_f32_16x16x32_f16, PLUS building
// row_ptr[0..n_rows] (CSR offsets) from the sorted adj_rows under the shadow
// of the pinned 16-deep feat load batch. row_ptr[r] = first edge index with
// row >= r (gap-filled for empty rows); row_ptr[n_rows] = n_edges.
// W staged in LDS pre-packed into B-fragment layout (validated round 8):
//   sWh[((ks*4+ct)*64 + l)*8 + j] = f16(W[ks*32 + (l>>4)*8 + j][ct*16+(l&15)])
// Block = 256 thr = 4 waves, each wave one 16-row x 64-col tile.
// ---------------------------------------------------------------------------
__global__ __launch_bounds__(256) void gemm_proj_mfma(
    const float* __restrict__ feat, const float* __restrict__ W,
    _Float16* __restrict__ projh, const int* __restrict__ rows,
    int* __restrict__ row_ptr, int n_rows, int n_edges)
{
    __shared__ _Float16 sWh[8 * 4 * 64 * 8];   // 16384 fp16 = 32 KB

    const int lane = threadIdx.x & 63;
    const int wave = threadIdx.x >> 6;
    const int row0 = blockIdx.x * 64 + wave * 16;
    const int kgrp = lane >> 4;            // 0..3
    int ar = row0 + (lane & 15);           // this lane's A row
    if (ar >= n_rows) ar = n_rows - 1;     // clamp; stores are guarded

    // Phase A: issue the full feat row-chunk (16 dwordx4) and pin the batch.
    f32x4 fa[16];
    const float* fp = feat + (size_t)ar * IN_FEAT + kgrp * 8;
    #pragma unroll
    for (int ks = 0; ks < 8; ++ks) {
        fa[2 * ks]     = *reinterpret_cast<const f32x4*>(fp + ks * 32);
        fa[2 * ks + 1] = *reinterpret_cast<const f32x4*>(fp + ks * 32 + 4);
    }
    __builtin_amdgcn_sched_barrier(0);     // keep all 16 loads issued here

    // Phase A': CSR row_ptr build (hides under the feat loads). ~4 edges/thr.
    {
        const int tid  = blockIdx.x * 256 + threadIdx.x;
        const int nthr = gridDim.x * 256;
        for (int e = tid; e < n_edges; e += nthr) {
            const int r = rows[e];
            if (e == 0) {
                for (int q = 0; q <= r; ++q) row_ptr[q] = 0;
            } else {
                const int rp = rows[e - 1];
                for (int q = rp + 1; q <= r; ++q) row_ptr[q] = e;
            }
            if (e == n_edges - 1) {
                for (int q = r + 1; q <= n_rows; ++q) row_ptr[q] = n_edges;
            }
        }
    }

    // Phase B: W -> fp16, packed to B-frag layout (coalesced, L2-hot).
    {
        const int c   = threadIdx.x & 63;        // W column (coalesced axis)
        const int kg0 = threadIdx.x >> 6;        // k-group 0..3 within iter
        #pragma unroll
        for (int it = 0; it < 8; ++it) {
            const int kg = it * 4 + kg0;         // k-group 0..31 (k = kg*8+j)
            HF8 tmp;
            #pragma unroll
            for (int j = 0; j < 8; ++j)
                tmp.h[j] = (_Float16)W[(kg * 8 + j) * OUT_FEAT + c];
            const int ks = kg >> 2;
            const int l  = (kg & 3) * 16 + (c & 15);
            const int ct = c >> 4;
            *reinterpret_cast<f16x8*>(&sWh[((ks * 4 + ct) * 64 + l) * 8]) = tmp.v;
        }
    }
    __syncthreads();
    if (row0 >= n_rows) return;            // after barrier: uniform participation

    f32x4 acc[4];
    #pragma unroll
    for (int ct = 0; ct < 4; ++ct) acc[ct] = f32x4{0.f, 0.f, 0.f, 0.f};

    #pragma unroll
    for (int ks = 0; ks < 8; ++ks) {
        HF8 A;
        #pragma unroll
        for (int h = 0; h < 2; ++h) {
            const f32x4 v = fa[2 * ks + h];
            #pragma unroll
            for (int j = 0; j < 4; ++j)
                A.h[h * 4 + j] = (_Float16)v[j];   // compiler packs: v_cvt_pk
        }
        #pragma unroll
        for (int ct = 0; ct < 4; ++ct) {
            HF8 B;
            B.v = *reinterpret_cast<const f16x8*>(
                &sWh[((ks * 4 + ct) * 64 + lane) * 8]);
            acc[ct] = __builtin_amdgcn_mfma_f32_16x16x32_f16(A.v, B.v, acc[ct], 0, 0, 0);
        }
    }

    #pragma unroll
    for (int r = 0; r < 4; ++r) {
        const int row = row0 + kgrp * 4 + r;
        if (row < n_rows) {
            #pragma unroll
            for (int ct = 0; ct < 4; ++ct)
                projh[(size_t)row * OUT_FEAT + ct * 16 + (lane & 15)] =
                    (_Float16)acc[ct][r];
        }
    }
}

// ---------------------------------------------------------------------------
// Kernel 2: out[row] = sum(val * proj[col]) over that row's edges.
// ROW-PARTITIONED: wave w exclusively owns rows [16w, 16w+16); its edge
// range [row_ptr[r0], row_ptr[r1]) is processed in 64-edge batches using the
// validated readlane-gather structure (coalesced metadata preload, 64
// static-readlane gathers pinned as a batch, segmented register accumulate).
// Every flush is a PLAIN STORE (no atomics anywhere); rows with no edges are
// zero-filled via a 16-bit flushed mask. Out is written exactly once/element.
// ---------------------------------------------------------------------------
__global__ __launch_bounds__(256) void gather_scatter(
    const _Float16* __restrict__ projh, const int* __restrict__ rows,
    const int* __restrict__ cols, const float* __restrict__ vals,
    const int* __restrict__ row_ptr, float* __restrict__ out, int n_rows)
{
    const int lane = threadIdx.x & 63;
    const int wid  = (blockIdx.x * 256 + threadIdx.x) >> 6;
    const int r0 = wid * RPW;
    if (r0 >= n_rows) return;
    const int r1 = min(r0 + RPW, n_rows);

    const int e_begin = row_ptr[r0];           // uniform scalar loads
    const int e_end   = row_ptr[r1];

    unsigned flushed = 0;                      // bit j -> row r0+j written

    if (e_begin < e_end) {
        float acc = 0.f;
        int cur = rows[e_begin];               // >= r0, < r1 by construction
        for (int b = e_begin; b < e_end; b += 64) {       // uniform trip
            const int rem = e_end - b;                     // > 0
            const int ee = (lane < rem) ? (b + lane) : (e_end - 1);
            const int r_v = rows[ee];
            const int c_v = cols[ee];
            const int v_bits = (lane < rem)
                                 ? __builtin_bit_cast(int, vals[ee]) : 0;

            // Issue all 64 gathers, pinned as a batch (full MLP).
            _Float16 p[64];
            #pragma unroll
            for (int i = 0; i < 64; ++i) {
                const int c = __builtin_amdgcn_readlane(c_v, i);   // SGPR
                p[i] = projh[(size_t)c * OUT_FEAT + lane];
            }
            __builtin_amdgcn_sched_barrier(0);

            // Segmented accumulate; flush = plain store (row wholly owned).
            // Clamped tail lanes have r == rows[e_end-1] == cur and v == 0.
            #pragma unroll
            for (int i = 0; i < 64; ++i) {
                const int   r = __builtin_amdgcn_readlane(r_v, i);  // SGPR
                const float v = __builtin_bit_cast(float,
                                    __builtin_amdgcn_readlane(v_bits, i));
                if (r != cur) {                                     // uniform
                    out[(size_t)cur * OUT_FEAT + lane] = acc;
                    flushed |= 1u << (cur - r0);
                    acc = 0.f;
                    cur = r;
                }
                acc = fmaf(v, (float)p[i], acc);
            }
        }
        out[(size_t)cur * OUT_FEAT + lane] = acc;          // final row
        flushed |= 1u << (cur - r0);
    }

    // Zero-fill rows with no edges (out is poisoned, must be 0).
    #pragma unroll
    for (int j = 0; j < RPW; ++j) {
        if (r0 + j < n_rows && !(flushed & (1u << j)))
            out[(size_t)(r0 + j) * OUT_FEAT + lane] = 0.f;
    }
}

extern "C" void kernel_launch(void* const* d_in, const int* in_sizes, int n_in,
                              void* d_out, int out_size, void* d_ws, size_t ws_size,
                              hipStream_t stream)
{
    const float* feat     = (const float*)d_in[0];
    const float* weight   = (const float*)d_in[1];
    const int*   adj_rows = (const int*)d_in[2];
    const int*   adj_cols = (const int*)d_in[3];
    const float* adj_vals = (const float*)d_in[4];
    float*       out      = (float*)d_out;

    const int n_nodes = in_sizes[0] / IN_FEAT;   // 100000
    const int n_edges = in_sizes[2];             // 1600000

    _Float16* projh   = (_Float16*)d_ws;                       // 12.8 MB
    int*      row_ptr = (int*)((char*)d_ws +
                        (size_t)n_nodes * OUT_FEAT * sizeof(_Float16));

    const int gemm_blocks = (n_nodes + 63) / 64;
    gemm_proj_mfma<<<gemm_blocks, 256, 0, stream>>>(feat, weight, projh,
                                                    adj_rows, row_ptr,
                                                    n_nodes, n_edges);

    const int waves  = (n_nodes + RPW - 1) / RPW;
    const int blocks = (waves + 3) / 4;
    gather_scatter<<<blocks, 256, 0, stream>>>(projh, adj_rows, adj_cols,
                                               adj_vals, row_ptr, out,
                                               n_nodes);
}